// Round 5
// baseline (137.415 us; speedup 1.0000x reference)
//
#include <hip/hip_runtime.h>
#include <hip/hip_bf16.h>

// RGCN CSR, two layers, MI355X.  Transform-then-gather (R3 structure).
//   xw1[(n*8+r)*64 + f] = (x @ W1[r])[n,f]   (dense GEMM, K=64, bf16 MFMA, f32 A read fused)
//   h[n,f] = relu( sum_{e in row n} xw1[(idx_e*8+rel_e)*64 + f] )
//   xw2[(n*8+r)*40 + f] = (h @ W2[r])[n,f]
//   out = log_softmax( sum_e xw2[...] )
// R5: gathers take 2 rows/wave (half-wave per row) with dword (2xbf16) loads —
// half the load instructions, 32 lines in flight per wave, no cross-half
// combine needed. Cast kernel folded into GEMM1's A-fragment load.

typedef __attribute__((ext_vector_type(8))) short short8;
typedef __attribute__((ext_vector_type(4))) float floatx4;

static __device__ __forceinline__ unsigned short f2bf(float f) {
    unsigned u = __float_as_uint(f);
    u += 0x7FFFu + ((u >> 16) & 1u);      // RNE
    return (unsigned short)(u >> 16);
}
static __device__ __forceinline__ float bflo(unsigned u) { return __uint_as_float(u << 16); }
static __device__ __forceinline__ float bfhi(unsigned u) { return __uint_as_float(u & 0xffff0000u); }

// ---- pack weights as B^T with K = input-feature dim ----
// BT1[j][d] = W1[r][d][f], j = r*64+f   (512 x 64)
// BT2[j][d] = W2[r][d][f], j = r*40+f   (320 x 64)
__global__ void k_packw(const float* __restrict__ W1, const float* __restrict__ W2,
                        unsigned short* __restrict__ BT1, unsigned short* __restrict__ BT2) {
    int i = blockIdx.x * 256 + threadIdx.x;
    if (i < 512 * 64) {
        int j = i >> 6, d = i & 63;
        int r = j >> 6, f = j & 63;
        BT1[i] = f2bf(W1[r * 4096 + d * 64 + f]);
    } else if (i < 512 * 64 + 320 * 64) {
        int ii = i - 512 * 64;
        int j = ii >> 6, d = ii & 63;
        int r = j / 40, f = j - r * 40;
        BT2[ii] = f2bf(W2[r * 2560 + d * 40 + f]);
    }
}

// ---- dense GEMM: xw[MP][NC] = A[MP][64] @ BT[NC][64]^T  (K=64, bf16 MFMA) ----
// AF32=1: A is f32 (x), rows >= M read as zero (fused cast). AF32=0: A bf16 (h).
// Block 256 thr = 4 waves; wave = 64 rows x 64 cols (4x4 frags); block = 256 rows.
template <int AF32>
__global__ __launch_bounds__(256) void k_xw(
    const void* __restrict__ Av, const unsigned short* __restrict__ BT,
    unsigned short* __restrict__ xw, int NC, int nColBlk, int M) {
    int bid = blockIdx.x;
    int cb = bid % nColBlk, rb = bid / nColBlk;
    int wave = threadIdx.x >> 6, lane = threadIdx.x & 63;
    int lr = lane & 15, lg = lane >> 4;
    int rowbase = rb * 256 + wave * 64;
    int col0 = cb * 64;
    floatx4 acc[4][4] = {};
#pragma unroll
    for (int k0 = 0; k0 < 2; ++k0) {
        int koff = k0 * 32 + lg * 8;
        short8 a[4], b[4];
#pragma unroll
        for (int mt = 0; mt < 4; ++mt) {
            int row = rowbase + mt * 16 + lr;
            if constexpr (AF32) {
                const float* Af = (const float*)Av;
                float4 v0 = {0, 0, 0, 0}, v1 = {0, 0, 0, 0};
                if (row < M) {
                    v0 = *(const float4*)(Af + (size_t)row * 64 + koff);
                    v1 = *(const float4*)(Af + (size_t)row * 64 + koff + 4);
                }
                short8 t;
                t[0] = (short)f2bf(v0.x); t[1] = (short)f2bf(v0.y);
                t[2] = (short)f2bf(v0.z); t[3] = (short)f2bf(v0.w);
                t[4] = (short)f2bf(v1.x); t[5] = (short)f2bf(v1.y);
                t[6] = (short)f2bf(v1.z); t[7] = (short)f2bf(v1.w);
                a[mt] = t;
            } else {
                const unsigned short* Ab = (const unsigned short*)Av;
                a[mt] = *(const short8*)(Ab + (size_t)row * 64 + koff);
            }
        }
#pragma unroll
        for (int nt = 0; nt < 4; ++nt)
            b[nt] = *(const short8*)(BT + (size_t)(col0 + nt * 16 + lr) * 64 + koff);
#pragma unroll
        for (int mt = 0; mt < 4; ++mt)
#pragma unroll
            for (int nt = 0; nt < 4; ++nt)
                acc[mt][nt] = __builtin_amdgcn_mfma_f32_16x16x32_bf16(a[mt], b[nt], acc[mt][nt], 0, 0, 0);
    }
    // C/D layout: col = lane&15, row = (lane>>4)*4 + i
#pragma unroll
    for (int mt = 0; mt < 4; ++mt)
#pragma unroll
        for (int nt = 0; nt < 4; ++nt)
#pragma unroll
            for (int i = 0; i < 4; ++i) {
                int row = rowbase + mt * 16 + lg * 4 + i;   // always < MP
                xw[(size_t)row * NC + col0 + nt * 16 + lr] = f2bf(acc[mt][nt][i]);
            }
}

// ---- gather-sum + relu -> h bf16 [MP][64]; zero pad rows ----
// 2 rows per wave: half-wave eo owns one row; lane loads dword (2 bf16) at
// feature pair fl. 16 dword loads in flight cover 32 cache lines.
__global__ __launch_bounds__(256) void k_gs_relu(
    const unsigned short* __restrict__ xw,   // viewed as [(n*8+r)][64]
    const int* __restrict__ ptr, const int* __restrict__ idx,
    const int* __restrict__ rel,
    unsigned short* __restrict__ H, int M, int MP) {
    int rowA = (blockIdx.x * 4 + (threadIdx.x >> 6)) * 2;
    if (rowA >= MP) return;
    rowA = __builtin_amdgcn_readfirstlane(rowA);
    int lane = threadIdx.x & 63;
    int fl = lane & 31, eo = lane >> 5;
    int rowB = rowA + 1;
    int myrow = eo ? rowB : rowA;
    if (rowA >= M) {                          // pad pair -> zeros
        *(unsigned*)(H + (size_t)myrow * 64 + fl * 2) = 0;
        return;
    }
    float cx = 0.f, cy = 0.f;
    bool both = (rowB < M);
    int p0 = ptr[rowA], p1 = ptr[rowA + 1];
    int p2 = both ? ptr[rowA + 2] : p1;
    if (both && (p1 - p0 == 16) && (p2 - p1 == 16)) {
        const int* ia = idx + p0; const int* ra_ = rel + p0;   // scalar (uniform)
        const int* ib = idx + p1; const int* rb_ = rel + p1;
        unsigned u[16];
#pragma unroll
        for (int t = 0; t < 16; ++t) {
            size_t bA = ((size_t)ia[t] * 8 + ra_[t]) * 128u;   // byte offsets, scalar
            size_t bB = ((size_t)ib[t] * 8 + rb_[t]) * 128u;
            size_t b = eo ? bB : bA;
            u[t] = *(const unsigned*)((const char*)xw + b + fl * 4);
        }
#pragma unroll
        for (int t = 0; t < 16; ++t) { cx += bflo(u[t]); cy += bfhi(u[t]); }
    } else {
        int ps = 0, deg = 0;
        if (myrow < M) { ps = ptr[myrow]; deg = ptr[myrow + 1] - ps; }
        for (int t = 0; t < deg; ++t) {
            int s = idx[ps + t], r = rel[ps + t];
            unsigned u = *(const unsigned*)((const char*)xw + ((size_t)s * 8 + r) * 128u + fl * 4);
            cx += bflo(u); cy += bfhi(u);
        }
    }
    unsigned o = ((unsigned)f2bf(fmaxf(cy, 0.f)) << 16) | f2bf(fmaxf(cx, 0.f));
    *(unsigned*)(H + (size_t)myrow * 64 + fl * 2) = o;
}

// ---- gather-sum + log_softmax -> out f32 [M][40] ----
// Same 2-rows/wave structure; row stride is 40 bf16 (80B); lanes fl<20 valid.
__global__ __launch_bounds__(256) void k_gs_lsm(
    const unsigned short* __restrict__ xw,   // viewed as [(n*8+r)][40]
    const int* __restrict__ ptr, const int* __restrict__ idx,
    const int* __restrict__ rel,
    float* __restrict__ out, int M) {
    int rowA = (blockIdx.x * 4 + (threadIdx.x >> 6)) * 2;
    if (rowA >= M) return;
    rowA = __builtin_amdgcn_readfirstlane(rowA);
    int lane = threadIdx.x & 63;
    int fl = lane & 31, eo = lane >> 5;
    int rowB = rowA + 1;
    int myrow = eo ? rowB : rowA;
    bool okf = fl < 20;
    int flc = okf ? fl : 0;
    float cx = 0.f, cy = 0.f;
    bool both = (rowB < M);
    int p0 = ptr[rowA], p1 = ptr[rowA + 1];
    int p2 = both ? ptr[rowA + 2] : p1;
    if (both && (p1 - p0 == 16) && (p2 - p1 == 16)) {
        const int* ia = idx + p0; const int* ra_ = rel + p0;
        const int* ib = idx + p1; const int* rb_ = rel + p1;
        unsigned u[16];
#pragma unroll
        for (int t = 0; t < 16; ++t) {
            size_t bA = ((size_t)ia[t] * 8 + ra_[t]) * 80u;
            size_t bB = ((size_t)ib[t] * 8 + rb_[t]) * 80u;
            size_t b = eo ? bB : bA;
            u[t] = *(const unsigned*)((const char*)xw + b + flc * 4);
        }
#pragma unroll
        for (int t = 0; t < 16; ++t) { cx += bflo(u[t]); cy += bfhi(u[t]); }
    } else {
        int ps = 0, deg = 0;
        if (myrow < M) { ps = ptr[myrow]; deg = ptr[myrow + 1] - ps; }
        for (int t = 0; t < deg; ++t) {
            int s = idx[ps + t], r = rel[ps + t];
            unsigned u = *(const unsigned*)((const char*)xw + ((size_t)s * 8 + r) * 80u + flc * 4);
            cx += bflo(u); cy += bfhi(u);
        }
    }
    // log-softmax over this half-wave's 40 values (lanes fl<20 hold 2 each)
    float mx = okf ? fmaxf(cx, cy) : -INFINITY;
#pragma unroll
    for (int m = 1; m < 32; m <<= 1) mx = fmaxf(mx, __shfl_xor(mx, m, 32));
    float s = okf ? (__expf(cx - mx) + __expf(cy - mx)) : 0.f;
#pragma unroll
    for (int m = 1; m < 32; m <<= 1) s += __shfl_xor(s, m, 32);
    float lse = mx + __logf(s);
    if (okf && myrow < M) {
        float2 o = {cx - lse, cy - lse};
        *(float2*)(out + (size_t)myrow * 40 + flc * 2) = o;
    }
}

extern "C" void kernel_launch(void* const* d_in, const int* in_sizes, int n_in,
                              void* d_out, int out_size, void* d_ws, size_t ws_size,
                              hipStream_t stream) {
    const float* x  = (const float*)d_in[0];
    const int* ptr  = (const int*)d_in[1];
    const int* idx  = (const int*)d_in[2];
    const int* rel  = (const int*)d_in[3];
    const float* W1 = (const float*)d_in[4];
    const float* W2 = (const float*)d_in[5];
    float* out = (float*)d_out;

    int N = in_sizes[1] - 1;                 // 75000
    int MP = (N + 255) & ~255;               // 75008 (multiple of 256)

    char* ws = (char*)d_ws;
    size_t szRow64 = (size_t)MP * 64 * 2;    // 9.6MB
    unsigned short* hbf = (unsigned short*)ws;
    unsigned short* BT1 = (unsigned short*)(ws + szRow64);
    unsigned short* BT2 = BT1 + 512 * 64;
    unsigned short* xwb = BT2 + 320 * 64;
    // xw1 [MP][512] = 76.8MB; xw2 [MP][320] aliases it.  Total ws ~= 86.5MB.

    k_packw<<<(512 * 64 + 320 * 64 + 255) / 256, 256, 0, stream>>>(W1, W2, BT1, BT2);

    int nrb = MP / 256;                      // 293
    // layer 1: xw1 = cast(x) @ W1 (NC=512, 8 col-blocks); A read as f32
    k_xw<1><<<nrb * 8, 256, 0, stream>>>((const void*)x, BT1, xwb, 512, 8, N);
    k_gs_relu<<<MP / 8, 256, 0, stream>>>(xwb, ptr, idx, rel, hbf, N, MP);
    // layer 2: xw2 = h @ W2 (NC=320, 5 col-blocks), aliases xwb
    k_xw<0><<<nrb * 5, 256, 0, stream>>>((const void*)hbf, BT2, xwb, 320, 5, MP);
    k_gs_lsm<<<(N + 7) / 8, 256, 0, stream>>>(xwb, ptr, idx, rel, out, N);
}

// Round 6
// 132.326 us; speedup vs baseline: 1.0385x; 1.0385x over previous
//
#include <hip/hip_runtime.h>
#include <hip/hip_bf16.h>

// RGCN CSR, two layers, MI355X.  Transform-then-gather.
//   xw1[(n*8+r)*64 + f] = (x @ W1[r])[n,f]   (dense GEMM, K=64, bf16 MFMA, f32 A fused-cast)
//   h[n,f] = relu( sum_{e in row n} xw1[(idx_e*8+rel_e)*64 + f] )
//   xw2[(n*8+r)*40 + f] = (h @ W2[r])[n,f]
//   out = log_softmax( sum_e xw2[...] )
// R6: k_xw restructured — col-block loop INSIDE the kernel, A-fragments loaded
// once into registers and reused across all col-blocks (R5 re-fetched A per
// col-block: 8x f32 fetch = 75MB -> latency-bound at 17% occupancy). B stays
// L2-hot (64KB). 32 rows/wave for VGPR headroom + 2344 waves of TLP.

typedef __attribute__((ext_vector_type(8))) short short8;
typedef __attribute__((ext_vector_type(4))) float floatx4;

static __device__ __forceinline__ unsigned short f2bf(float f) {
    unsigned u = __float_as_uint(f);
    u += 0x7FFFu + ((u >> 16) & 1u);      // RNE
    return (unsigned short)(u >> 16);
}
static __device__ __forceinline__ float bflo(unsigned u) { return __uint_as_float(u << 16); }
static __device__ __forceinline__ float bfhi(unsigned u) { return __uint_as_float(u & 0xffff0000u); }

// ---- pack weights as B^T with K = input-feature dim ----
// BT1[j][d] = W1[r][d][f], j = r*64+f   (512 x 64)
// BT2[j][d] = W2[r][d][f], j = r*40+f   (320 x 64)
__global__ void k_packw(const float* __restrict__ W1, const float* __restrict__ W2,
                        unsigned short* __restrict__ BT1, unsigned short* __restrict__ BT2) {
    int i = blockIdx.x * 256 + threadIdx.x;
    if (i < 512 * 64) {
        int j = i >> 6, d = i & 63;
        int r = j >> 6, f = j & 63;
        BT1[i] = f2bf(W1[r * 4096 + d * 64 + f]);
    } else if (i < 512 * 64 + 320 * 64) {
        int ii = i - 512 * 64;
        int j = ii >> 6, d = ii & 63;
        int r = j / 40, f = j - r * 40;
        BT2[ii] = f2bf(W2[r * 2560 + d * 40 + f]);
    }
}

// ---- dense GEMM: xw[MP][NC] = A[MP][64] @ BT[NC][64]^T  (K=64, bf16 MFMA) ----
// AF32=1: A is f32 (x), rows >= M read as zero (fused cast). AF32=0: A bf16 (h).
// Wave owns 32 rows; A-frags in registers; loop over nColBlk 64-col slabs.
template <int AF32>
__global__ __launch_bounds__(256) void k_xw(
    const void* __restrict__ Av, const unsigned short* __restrict__ BT,
    unsigned short* __restrict__ xw, int NC, int nColBlk, int M) {
    int wave = threadIdx.x >> 6, lane = threadIdx.x & 63;
    int lr = lane & 15, lg = lane >> 4;
    int rowbase = (blockIdx.x * 4 + wave) * 32;

    short8 af[2][2];                          // [mt][k0] — A read exactly once
#pragma unroll
    for (int mt = 0; mt < 2; ++mt)
#pragma unroll
        for (int k0 = 0; k0 < 2; ++k0) {
            int row = rowbase + mt * 16 + lr;
            int koff = k0 * 32 + lg * 8;
            if constexpr (AF32) {
                const float* Af = (const float*)Av;
                float4 v0 = {0, 0, 0, 0}, v1 = {0, 0, 0, 0};
                if (row < M) {
                    v0 = *(const float4*)(Af + (size_t)row * 64 + koff);
                    v1 = *(const float4*)(Af + (size_t)row * 64 + koff + 4);
                }
                short8 t;
                t[0] = (short)f2bf(v0.x); t[1] = (short)f2bf(v0.y);
                t[2] = (short)f2bf(v0.z); t[3] = (short)f2bf(v0.w);
                t[4] = (short)f2bf(v1.x); t[5] = (short)f2bf(v1.y);
                t[6] = (short)f2bf(v1.z); t[7] = (short)f2bf(v1.w);
                af[mt][k0] = t;
            } else {
                const unsigned short* Ab = (const unsigned short*)Av;
                af[mt][k0] = *(const short8*)(Ab + (size_t)row * 64 + koff);
            }
        }

    for (int cb = 0; cb < nColBlk; ++cb) {
        int col0 = cb * 64;
        floatx4 acc[2][4] = {};
#pragma unroll
        for (int k0 = 0; k0 < 2; ++k0) {
            int koff = k0 * 32 + lg * 8;
            short8 b[4];
#pragma unroll
            for (int nt = 0; nt < 4; ++nt)
                b[nt] = *(const short8*)(BT + (size_t)(col0 + nt * 16 + lr) * 64 + koff);
#pragma unroll
            for (int mt = 0; mt < 2; ++mt)
#pragma unroll
                for (int nt = 0; nt < 4; ++nt)
                    acc[mt][nt] = __builtin_amdgcn_mfma_f32_16x16x32_bf16(af[mt][k0], b[nt], acc[mt][nt], 0, 0, 0);
        }
        // C/D layout: col = lane&15, row = (lane>>4)*4 + i
#pragma unroll
        for (int mt = 0; mt < 2; ++mt)
#pragma unroll
            for (int nt = 0; nt < 4; ++nt)
#pragma unroll
                for (int i = 0; i < 4; ++i) {
                    int row = rowbase + mt * 16 + lg * 4 + i;   // always < MP
                    xw[(size_t)row * NC + col0 + nt * 16 + lr] = f2bf(acc[mt][nt][i]);
                }
    }
}

// ---- gather-sum + relu -> h bf16 [MP][64]; zero pad rows ----
// 2 rows per wave: half-wave eo owns one row; lane loads dword (2 bf16) at
// feature pair fl. 16 dword loads in flight cover 32 cache lines.
__global__ __launch_bounds__(256) void k_gs_relu(
    const unsigned short* __restrict__ xw,   // viewed as [(n*8+r)][64]
    const int* __restrict__ ptr, const int* __restrict__ idx,
    const int* __restrict__ rel,
    unsigned short* __restrict__ H, int M, int MP) {
    int rowA = (blockIdx.x * 4 + (threadIdx.x >> 6)) * 2;
    if (rowA >= MP) return;
    rowA = __builtin_amdgcn_readfirstlane(rowA);
    int lane = threadIdx.x & 63;
    int fl = lane & 31, eo = lane >> 5;
    int rowB = rowA + 1;
    int myrow = eo ? rowB : rowA;
    if (rowA >= M) {                          // pad pair -> zeros
        *(unsigned*)(H + (size_t)myrow * 64 + fl * 2) = 0;
        return;
    }
    float cx = 0.f, cy = 0.f;
    bool both = (rowB < M);
    int p0 = ptr[rowA], p1 = ptr[rowA + 1];
    int p2 = both ? ptr[rowA + 2] : p1;
    if (both && (p1 - p0 == 16) && (p2 - p1 == 16)) {
        const int* ia = idx + p0; const int* ra_ = rel + p0;   // scalar (uniform)
        const int* ib = idx + p1; const int* rb_ = rel + p1;
        unsigned u[16];
#pragma unroll
        for (int t = 0; t < 16; ++t) {
            size_t bA = ((size_t)ia[t] * 8 + ra_[t]) * 128u;   // byte offsets, scalar
            size_t bB = ((size_t)ib[t] * 8 + rb_[t]) * 128u;
            size_t b = eo ? bB : bA;
            u[t] = *(const unsigned*)((const char*)xw + b + fl * 4);
        }
#pragma unroll
        for (int t = 0; t < 16; ++t) { cx += bflo(u[t]); cy += bfhi(u[t]); }
    } else {
        int ps = 0, deg = 0;
        if (myrow < M) { ps = ptr[myrow]; deg = ptr[myrow + 1] - ps; }
        for (int t = 0; t < deg; ++t) {
            int s = idx[ps + t], r = rel[ps + t];
            unsigned u = *(const unsigned*)((const char*)xw + ((size_t)s * 8 + r) * 128u + fl * 4);
            cx += bflo(u); cy += bfhi(u);
        }
    }
    unsigned o = ((unsigned)f2bf(fmaxf(cy, 0.f)) << 16) | f2bf(fmaxf(cx, 0.f));
    *(unsigned*)(H + (size_t)myrow * 64 + fl * 2) = o;
}

// ---- gather-sum + log_softmax -> out f32 [M][40] ----
// Same 2-rows/wave structure; row stride is 40 bf16 (80B); lanes fl<20 valid.
__global__ __launch_bounds__(256) void k_gs_lsm(
    const unsigned short* __restrict__ xw,   // viewed as [(n*8+r)][40]
    const int* __restrict__ ptr, const int* __restrict__ idx,
    const int* __restrict__ rel,
    float* __restrict__ out, int M) {
    int rowA = (blockIdx.x * 4 + (threadIdx.x >> 6)) * 2;
    if (rowA >= M) return;
    rowA = __builtin_amdgcn_readfirstlane(rowA);
    int lane = threadIdx.x & 63;
    int fl = lane & 31, eo = lane >> 5;
    int rowB = rowA + 1;
    int myrow = eo ? rowB : rowA;
    bool okf = fl < 20;
    int flc = okf ? fl : 0;
    float cx = 0.f, cy = 0.f;
    bool both = (rowB < M);
    int p0 = ptr[rowA], p1 = ptr[rowA + 1];
    int p2 = both ? ptr[rowA + 2] : p1;
    if (both && (p1 - p0 == 16) && (p2 - p1 == 16)) {
        const int* ia = idx + p0; const int* ra_ = rel + p0;
        const int* ib = idx + p1; const int* rb_ = rel + p1;
        unsigned u[16];
#pragma unroll
        for (int t = 0; t < 16; ++t) {
            size_t bA = ((size_t)ia[t] * 8 + ra_[t]) * 80u;
            size_t bB = ((size_t)ib[t] * 8 + rb_[t]) * 80u;
            size_t b = eo ? bB : bA;
            u[t] = *(const unsigned*)((const char*)xw + b + flc * 4);
        }
#pragma unroll
        for (int t = 0; t < 16; ++t) { cx += bflo(u[t]); cy += bfhi(u[t]); }
    } else {
        int ps = 0, deg = 0;
        if (myrow < M) { ps = ptr[myrow]; deg = ptr[myrow + 1] - ps; }
        for (int t = 0; t < deg; ++t) {
            int s = idx[ps + t], r = rel[ps + t];
            unsigned u = *(const unsigned*)((const char*)xw + ((size_t)s * 8 + r) * 80u + flc * 4);
            cx += bflo(u); cy += bfhi(u);
        }
    }
    // log-softmax over this half-wave's 40 values (lanes fl<20 hold 2 each)
    float mx = okf ? fmaxf(cx, cy) : -INFINITY;
#pragma unroll
    for (int m = 1; m < 32; m <<= 1) mx = fmaxf(mx, __shfl_xor(mx, m, 32));
    float s = okf ? (__expf(cx - mx) + __expf(cy - mx)) : 0.f;
#pragma unroll
    for (int m = 1; m < 32; m <<= 1) s += __shfl_xor(s, m, 32);
    float lse = mx + __logf(s);
    if (okf && myrow < M) {
        float2 o = {cx - lse, cy - lse};
        *(float2*)(out + (size_t)myrow * 40 + flc * 2) = o;
    }
}

extern "C" void kernel_launch(void* const* d_in, const int* in_sizes, int n_in,
                              void* d_out, int out_size, void* d_ws, size_t ws_size,
                              hipStream_t stream) {
    const float* x  = (const float*)d_in[0];
    const int* ptr  = (const int*)d_in[1];
    const int* idx  = (const int*)d_in[2];
    const int* rel  = (const int*)d_in[3];
    const float* W1 = (const float*)d_in[4];
    const float* W2 = (const float*)d_in[5];
    float* out = (float*)d_out;

    int N = in_sizes[1] - 1;                 // 75000
    int MP = (N + 255) & ~255;               // 75008 (multiple of 256 -> of 128 too)

    char* ws = (char*)d_ws;
    size_t szRow64 = (size_t)MP * 64 * 2;    // 9.6MB
    unsigned short* hbf = (unsigned short*)ws;
    unsigned short* BT1 = (unsigned short*)(ws + szRow64);
    unsigned short* BT2 = BT1 + 512 * 64;
    unsigned short* xwb = BT2 + 320 * 64;
    // xw1 [MP][512] = 76.8MB; xw2 [MP][320] aliases it.  Total ws ~= 86.5MB.

    k_packw<<<(512 * 64 + 320 * 64 + 255) / 256, 256, 0, stream>>>(W1, W2, BT1, BT2);

    int nblk = MP / 128;                     // 586 blocks, 4 waves x 32 rows
    // layer 1: xw1 = cast(x) @ W1 (NC=512, 8 col-slabs); A f32 read ONCE
    k_xw<1><<<nblk, 256, 0, stream>>>((const void*)x, BT1, xwb, 512, 8, N);
    k_gs_relu<<<MP / 8, 256, 0, stream>>>(xwb, ptr, idx, rel, hbf, N, MP);
    // layer 2: xw2 = h @ W2 (NC=320, 5 col-slabs), aliases xwb
    k_xw<0><<<nblk, 256, 0, stream>>>((const void*)hbf, BT2, xwb, 320, 5, MP);
    k_gs_lsm<<<(N + 7) / 8, 256, 0, stream>>>(xwb, ptr, idx, rel, out, N);
}